// Round 9
// baseline (1496.748 us; speedup 1.0000x reference)
//
#include <hip/hip_runtime.h>
#include <hip/hip_cooperative_groups.h>

namespace cg = cooperative_groups;

// Problem constants (match reference)
#define BATCHN 32
#define NCELL  4096
#define BN     (BATCHN * NCELL)

// Round 9: R7 kernel + single cooperative launch.
// R8 falsified pure latency-bound (2 waves/SIMD at 4x redundancy = +58 us,
// i.e. exactly the added issue). Surviving model: dur = 10 x (OH + K),
// OH ~5-10 us per dependent dispatch in the graph, K ~1.5-2x issue.
// This round removes 9 of 10 dispatch boundaries: one cooperative kernel
// runs all 600 steps; every 60 steps: __threadfence + grid.sync() + reload
// the 256-cell window from the just-written trajectory plane (neighbor
// waves wrote our halo cells -- same values a relaunch would have read).
// Math is bit-identical to R7 (absmax expected unchanged: 0.00390625).
constexpr int OWN    = 128;
constexpr int HALO   = 64;
constexpr int CPL    = 4;                  // cells per lane
constexpr int KSTEP  = 60;                 // steps per sync interval (< HALO)
constexpr int CHUNKS = NCELL / OWN;        // 32

typedef float v2f __attribute__((ext_vector_type(2)));

// hf = 0.5*f_real(u), ha = 0.5*|f_real'(u)| — monomial expansion, 0.5
// pre-folded (verified vs reference at u=1: f=1,f'=0; u=0.5: f=0.710286,
// f'=1.085938). Flux uses 0.5*max(a,b) == max(0.5a,0.5b) exactly.
__device__ __forceinline__ void eval2(v2f u, v2f& hf, v2f& ha) {
    v2f u2 = u * u;
    v2f u3 = u2 * u;
    v2f p1 = u * 0.3125f + 0.75f;
    v2f A  = u * p1;                               // 0.75u + 0.3125u^2
    v2f p2 = u * 0.625f + (-1.0833333333333333f);  // -13/12 + 0.625u
    v2f B  = u3 * p2 + A;
    v2f u6 = u3 * u3;
    hf = u6 * (-0.10416666666666667f) + B;         // -5/48 u^6
    v2f p3 = u * 0.625f + 0.75f;
    v2f p4 = u * 2.5f + (-3.25f);
    v2f C  = u2 * p4 + p3;                         // 0.75+0.625u-3.25u^2+2.5u^3
    v2f u5 = u2 * u3;
    v2f hd = u5 * (-0.625f) + C;
    ha.x = fabsf(hd.x);
    ha.y = fabsf(hd.y);
}

__device__ __forceinline__ float bperm(int addr4, float v) {
    return __int_as_float(__builtin_amdgcn_ds_bpermute(addr4, __float_as_int(v)));
}

// One LF step on 4 cells/lane held as P=(u0,u3), Q=(u1,u2).
__device__ __forceinline__ void lf_step(v2f& P, v2f& Q, float n[CPL],
                                        int aL, int aR, bool bcL, bool bcR,
                                        float dtdx) {
    // edge pair first -> bpermutes issue as early as possible
    v2f hfP, haP;
    eval2(P, hfP, haP);
    float ul  = bperm(aL, P.y);    // left neighbor's cell 3
    float hfl = bperm(aL, hfP.y);
    float hal = bperm(aL, haP.y);
    float ur  = bperm(aR, P.x);    // right neighbor's cell 0
    float hfr = bperm(aR, hfP.x);
    float har = bperm(aR, haP.x);

    // inner pair eval overlaps the DS latency
    v2f hfQ, haQ;
    eval2(Q, hfQ, haQ);

    // 5 interface fluxes (0.5 pre-folded into hf/ha)
    float fh0 = (hfl   + hfP.x) - fmaxf(hal,   haP.x) * (P.x - ul);
    float fh1 = (hfP.x + hfQ.x) - fmaxf(haP.x, haQ.x) * (Q.x - P.x);
    float fh2 = (hfQ.x + hfQ.y) - fmaxf(haQ.x, haQ.y) * (Q.y - Q.x);
    float fh3 = (hfQ.y + hfP.y) - fmaxf(haQ.y, haP.y) * (P.y - Q.y);
    float fh4 = (hfP.y + hfr  ) - fmaxf(haP.y, har  ) * (ur  - P.y);

    n[0] = P.x - dtdx * (fh1 - fh0);
    n[1] = Q.x - dtdx * (fh2 - fh1);
    n[2] = Q.y - dtdx * (fh3 - fh2);
    n[3] = P.y - dtdx * (fh4 - fh3);

    // outflow BCs: u[0]=u[1], u[N-1]=u[N-2] (firewall against halo garbage)
    if (bcL) n[0] = n[1];
    if (bcR) n[3] = n[2];

    P.x = n[0]; P.y = n[3];
    Q.x = n[1]; Q.y = n[2];
}

__global__ __launch_bounds__(64) void lf_all(const float* __restrict__ init,
                                             float* __restrict__ out,
                                             int total) {
    cg::grid_group grid = cg::this_grid();

    const int lane  = threadIdx.x;          // one wave per block
    const int wid   = blockIdx.x;
    const int chunk = wid & (CHUNKS - 1);
    const int row   = wid >> 5;             // CHUNKS == 32
    const int gbase = chunk * OWN - HALO;
    const int c0    = lane * CPL;

    const float dtdx = (float)(0.0009 / (10.0 / 4096.0));

    // clamped neighbor-lane byte addresses (edge lanes read self; the
    // 60-step contamination cone never reaches owned cells [64,192))
    const int aL = max(lane - 1, 0) * 4;
    const int aR = min(lane + 1, 63) * 4;

    // clamped global indices for (re)loading the 256-cell window
    int gidx[CPL];
    #pragma unroll
    for (int j = 0; j < CPL; ++j) {
        int g = gbase + c0 + j;
        gidx[j] = min(max(g, 0), NCELL - 1);
    }

    v2f P, Q;
    {
        const float* ip = init + (size_t)row * NCELL;
        float u0 = ip[gidx[0]], u1 = ip[gidx[1]], u2 = ip[gidx[2]], u3 = ip[gidx[3]];
        P.x = u0; P.y = u3;
        Q.x = u1; Q.y = u2;
    }

    // owned cells [64,192) -> lanes 16..47 (all 4 cells contiguous)
    const bool owned = (lane >= 16) && (lane < 48);
    const bool bcL = (chunk == 0) && (lane == 16);            // global cell 0
    const bool bcR = (chunk == CHUNKS - 1) && (lane == 47);   // global cell N-1

    for (int s = 0; s < total; s += KSTEP) {
        const int ns = (total - s) < KSTEP ? (total - s) : KSTEP;
        float* op = out + (size_t)(s + 1) * BN + (size_t)row * NCELL + (gbase + c0);

        int t = 0;
        // groups of 4 steps, stores batched per group (R4 scheme, kept)
        for (; t + 4 <= ns; t += 4) {
            float b0[CPL], b1[CPL], b2[CPL], b3[CPL];
            lf_step(P, Q, b0, aL, aR, bcL, bcR, dtdx);
            lf_step(P, Q, b1, aL, aR, bcL, bcR, dtdx);
            lf_step(P, Q, b2, aL, aR, bcL, bcR, dtdx);
            lf_step(P, Q, b3, aL, aR, bcL, bcR, dtdx);
            if (owned) {
                *(float4*)(op)            = make_float4(b0[0], b0[1], b0[2], b0[3]);
                *(float4*)(op + BN)       = make_float4(b1[0], b1[1], b1[2], b1[3]);
                *(float4*)(op + 2 * BN)   = make_float4(b2[0], b2[1], b2[2], b2[3]);
                *(float4*)(op + 3 * BN)   = make_float4(b3[0], b3[1], b3[2], b3[3]);
            }
            op += 4 * BN;
        }
        for (; t < ns; ++t) {
            float n[CPL];
            lf_step(P, Q, n, aL, aR, bcL, bcR, dtdx);
            if (owned) *(float4*)op = make_float4(n[0], n[1], n[2], n[3]);
            op += BN;
        }

        // refresh the window (incl. halo written by neighbor waves) before
        // the next 60-step block -- replaces a kernel relaunch.
        if (s + ns < total) {
            __threadfence();
            grid.sync();
            const float* rp = out + (size_t)(s + ns) * BN + (size_t)row * NCELL;
            float u0 = rp[gidx[0]], u1 = rp[gidx[1]], u2 = rp[gidx[2]], u3 = rp[gidx[3]];
            P.x = u0; P.y = u3;
            Q.x = u1; Q.y = u2;
        }
    }
}

extern "C" void kernel_launch(void* const* d_in, const int* in_sizes, int n_in,
                              void* d_out, int out_size, void* d_ws, size_t ws_size,
                              hipStream_t stream) {
    const float* init = (const float*)d_in[0];
    float* out = (float*)d_out;

    int total = out_size / BN - 1;

    // plane 0 = init
    hipMemcpyAsync(d_out, init, (size_t)BN * sizeof(float),
                   hipMemcpyDeviceToDevice, stream);

    dim3 grid(CHUNKS * BATCHN);   // 1024 blocks, 1 wave each (1/SIMD chip-wide)
    dim3 block(64);
    void* args[] = { (void*)&init, (void*)&out, (void*)&total };
    hipLaunchCooperativeKernel((const void*)lf_all, grid, block, args, 0, stream);
}

// Round 10
// 151.529 us; speedup vs baseline: 9.8777x; 9.8777x over previous
//
#include <hip/hip_runtime.h>

// Problem constants (match reference)
#define BATCHN 32
#define NCELL  4096
#define BN     (BATCHN * NCELL)

// Round 10: R7 structure, DS-pipe-free halo exchange via DPP.
// Evidence chain: R8 (2 waves/SIMD = +exactly the added issue, no hiding)
// => stalled resource is shared per-CU => DS pipe + lgkmcnt waits from the
// 6 ds_bpermute/step. R9's profile (VALUBusy 4.6% over the coop kernel)
// confirms waves are ~65% stalled. Fix: wave_shr:1 / wave_shl:1 DPP
// (gfx9-lineage, VALU pipe, no DS op, no lgkmcnt). update_dpp with
// old=self + bound_ctrl=false keeps self at the shifted-in lane edge ==
// R7's clamped-address semantics exactly -> bit-identical results.
constexpr int OWN    = 128;
constexpr int HALO   = 64;
constexpr int CPL    = 4;                  // cells per lane
constexpr int KSTEP  = 60;                 // steps per launch (< HALO)
constexpr int CHUNKS = NCELL / OWN;        // 32

typedef float v2f __attribute__((ext_vector_type(2)));

// hf = 0.5*f_real(u), ha = 0.5*|f_real'(u)| — monomial expansion, 0.5
// pre-folded (verified vs reference at u=1: f=1,f'=0; u=0.5: f=0.710286,
// f'=1.085938). Flux uses 0.5*max(a,b) == max(0.5a,0.5b) exactly.
__device__ __forceinline__ void eval2(v2f u, v2f& hf, v2f& ha) {
    v2f u2 = u * u;
    v2f u3 = u2 * u;
    v2f p1 = u * 0.3125f + 0.75f;
    v2f A  = u * p1;                               // 0.75u + 0.3125u^2
    v2f p2 = u * 0.625f + (-1.0833333333333333f);  // -13/12 + 0.625u
    v2f B  = u3 * p2 + A;
    v2f u6 = u3 * u3;
    hf = u6 * (-0.10416666666666667f) + B;         // -5/48 u^6
    v2f p3 = u * 0.625f + 0.75f;
    v2f p4 = u * 2.5f + (-3.25f);
    v2f C  = u2 * p4 + p3;                         // 0.75+0.625u-3.25u^2+2.5u^3
    v2f u5 = u2 * u3;
    v2f hd = u5 * (-0.625f) + C;
    ha.x = fabsf(hd.x);
    ha.y = fabsf(hd.y);
}

// lane i <- lane i-1 (edge lane keeps self): DPP WAVE_SHR:1 = 0x138
__device__ __forceinline__ float dpp_left(float v) {
    int i = __float_as_int(v);
    return __int_as_float(
        __builtin_amdgcn_update_dpp(i, i, 0x138, 0xF, 0xF, false));
}
// lane i <- lane i+1 (edge lane keeps self): DPP WAVE_SHL:1 = 0x130
__device__ __forceinline__ float dpp_right(float v) {
    int i = __float_as_int(v);
    return __int_as_float(
        __builtin_amdgcn_update_dpp(i, i, 0x130, 0xF, 0xF, false));
}

// One LF step on 4 cells/lane held as P=(u0,u3), Q=(u1,u2).
__device__ __forceinline__ void lf_step(v2f& P, v2f& Q, float n[CPL],
                                        bool bcL, bool bcR, float dtdx) {
    v2f hfP, haP;
    eval2(P, hfP, haP);
    // halo exchange in the VALU pipe (DPP) — no DS op, no lgkmcnt wait
    float ul  = dpp_left(P.y);     // left neighbor's cell 3
    float hfl = dpp_left(hfP.y);
    float hal = dpp_left(haP.y);
    float ur  = dpp_right(P.x);    // right neighbor's cell 0
    float hfr = dpp_right(hfP.x);
    float har = dpp_right(haP.x);

    v2f hfQ, haQ;
    eval2(Q, hfQ, haQ);

    // 5 interface fluxes (0.5 pre-folded into hf/ha)
    float fh0 = (hfl   + hfP.x) - fmaxf(hal,   haP.x) * (P.x - ul);
    float fh1 = (hfP.x + hfQ.x) - fmaxf(haP.x, haQ.x) * (Q.x - P.x);
    float fh2 = (hfQ.x + hfQ.y) - fmaxf(haQ.x, haQ.y) * (Q.y - Q.x);
    float fh3 = (hfQ.y + hfP.y) - fmaxf(haQ.y, haP.y) * (P.y - Q.y);
    float fh4 = (hfP.y + hfr  ) - fmaxf(haP.y, har  ) * (ur  - P.y);

    n[0] = P.x - dtdx * (fh1 - fh0);
    n[1] = Q.x - dtdx * (fh2 - fh1);
    n[2] = Q.y - dtdx * (fh3 - fh2);
    n[3] = P.y - dtdx * (fh4 - fh3);

    // outflow BCs: u[0]=u[1], u[N-1]=u[N-2] (firewall against halo garbage)
    if (bcL) n[0] = n[1];
    if (bcR) n[3] = n[2];

    P.x = n[0]; P.y = n[3];
    Q.x = n[1]; Q.y = n[2];
}

__global__ __launch_bounds__(64) void lf_wave(const float* __restrict__ in_state,
                                              float* __restrict__ out,
                                              int s0, int nsteps) {
    const int lane  = threadIdx.x;          // one wave per block
    const int wid   = blockIdx.x;
    const int chunk = wid & (CHUNKS - 1);
    const int row   = wid >> 5;             // CHUNKS == 32
    const int gbase = chunk * OWN - HALO;
    const int c0    = lane * CPL;

    const float dtdx = (float)(0.0009 / (10.0 / 4096.0));

    float uin[CPL];
    {
        const float* ip = in_state + (size_t)row * NCELL;
        #pragma unroll
        for (int j = 0; j < CPL; ++j) {
            int g = gbase + c0 + j;
            g = min(max(g, 0), NCELL - 1);
            uin[j] = ip[g];
        }
    }
    v2f P, Q;
    P.x = uin[0]; P.y = uin[3];
    Q.x = uin[1]; Q.y = uin[2];

    // owned cells [64,192) -> lanes 16..47 (all 4 cells contiguous)
    const bool owned = (lane >= 16) && (lane < 48);
    const bool bcL = (chunk == 0) && (lane == 16);            // global cell 0
    const bool bcR = (chunk == CHUNKS - 1) && (lane == 47);   // global cell N-1

    float* op = out + (size_t)(s0 + 1) * BN + (size_t)row * NCELL + (gbase + c0);

    int t = 0;
    // groups of 4 steps, stores batched per group (R4 scheme, kept)
    for (; t + 4 <= nsteps; t += 4) {
        float b0[CPL], b1[CPL], b2[CPL], b3[CPL];
        lf_step(P, Q, b0, bcL, bcR, dtdx);
        lf_step(P, Q, b1, bcL, bcR, dtdx);
        lf_step(P, Q, b2, bcL, bcR, dtdx);
        lf_step(P, Q, b3, bcL, bcR, dtdx);
        if (owned) {
            *(float4*)(op)            = make_float4(b0[0], b0[1], b0[2], b0[3]);
            *(float4*)(op + BN)       = make_float4(b1[0], b1[1], b1[2], b1[3]);
            *(float4*)(op + 2 * BN)   = make_float4(b2[0], b2[1], b2[2], b2[3]);
            *(float4*)(op + 3 * BN)   = make_float4(b3[0], b3[1], b3[2], b3[3]);
        }
        op += 4 * BN;
    }
    // tail (not hit for nsteps=60, kept for robustness)
    for (; t < nsteps; ++t) {
        float n[CPL];
        lf_step(P, Q, n, bcL, bcR, dtdx);
        if (owned) *(float4*)op = make_float4(n[0], n[1], n[2], n[3]);
        op += BN;
    }
}

extern "C" void kernel_launch(void* const* d_in, const int* in_sizes, int n_in,
                              void* d_out, int out_size, void* d_ws, size_t ws_size,
                              hipStream_t stream) {
    const float* init = (const float*)d_in[0];
    float* out = (float*)d_out;

    const int total = out_size / BN - 1;

    // plane 0 = init
    hipMemcpyAsync(d_out, init, (size_t)BN * sizeof(float),
                   hipMemcpyDeviceToDevice, stream);

    const int nblocks = CHUNKS * BATCHN;    // 1024 waves, 1/SIMD chip-wide
    for (int s = 0; s < total; s += KSTEP) {
        int ns = (total - s) < KSTEP ? (total - s) : KSTEP;
        lf_wave<<<nblocks, 64, 0, stream>>>(out + (size_t)s * BN, out, s, ns);
    }
}